// Round 1
// baseline (61102.844 us; speedup 1.0000x reference)
//
#include <hip/hip_runtime.h>

// SimpleLSTM: B=64, T=2048, H=512, input dim 1.
// Design: persistent grid-synced kernel on 256 WGs (one per CU).
//   WG w -> batch tile bt = w&3 (16 batches), unit tile rt = w>>2 (8 units).
//   Each WG owns rows {g*512 + rt*8 + j : g in 0..3, j in 0..7} (32 rows) x 16 batches.
//   Per step: stage h_prev tile (16x512) into LDS, dot vs W_hh rows (fp32, L1-resident,
//   64KB/step/CU), gate nonlinearities, c update in registers, h -> double-buffered
//   global hbuf, y[b][t] via shfl-reduce + atomicAdd, then 2-level device barrier.

#define TT 2048
#define BB 64
#define HH 512
#define Y_OFF 0
#define HN_OFF (BB * TT)
#define CN_OFF (BB * TT + BB * HH)

// ---- 2-level monotonic grid barrier ------------------------------------
// cnt[0]            : main counter (16 increments per barrier)
// cnt[32*(1+g)]     : sub counter for group g (16 blocks each), 128B apart
__device__ __forceinline__ void grid_barrier(unsigned* __restrict__ cnt, int bar_idx) {
    __syncthreads();
    if (threadIdx.x == 0) {
        const int g = blockIdx.x >> 4;  // 16 groups of 16 blocks
        unsigned* sub = cnt + 32 * (1 + g);
        const unsigned old =
            __hip_atomic_fetch_add(sub, 1u, __ATOMIC_ACQ_REL, __HIP_MEMORY_SCOPE_AGENT);
        const unsigned tgt = (unsigned)(bar_idx + 1) * 16u;
        if (old == tgt - 1u) {  // last of group: escalate (acq_rel chains releases)
            __hip_atomic_fetch_add(cnt, 1u, __ATOMIC_ACQ_REL, __HIP_MEMORY_SCOPE_AGENT);
        }
        while (__hip_atomic_load(cnt, __ATOMIC_ACQUIRE, __HIP_MEMORY_SCOPE_AGENT) < tgt) {
            __builtin_amdgcn_s_sleep(2);  // ~128 cyc backoff between polls
        }
    }
    __syncthreads();
}

__global__ __launch_bounds__(256, 1)
void lstm_persistent(const float* __restrict__ x,     // [B][T]
                     const float* __restrict__ Wih,   // [4H]
                     const float* __restrict__ Whh,   // [4H][H]
                     const float* __restrict__ bih,   // [4H]
                     const float* __restrict__ bhh,   // [4H]
                     const float* __restrict__ Wfc,   // [H]
                     const float* __restrict__ bfc,   // [1]
                     float* __restrict__ out,         // y | h_n | c_n
                     float* __restrict__ hbuf,        // [2][B][H] (pre-zeroed)
                     unsigned* __restrict__ cnt)      // barrier counters (pre-zeroed)
{
    const int w   = blockIdx.x;   // 0..255
    const int bt  = w & 3;        // batch tile
    const int rt  = w >> 2;       // unit tile 0..63
    const int tid = threadIdx.x;

    __shared__ float hs[16 * HH];   // staged h_prev tile, 32KB
    __shared__ float gs[16][32];    // gate preactivations, 2KB

    // ---- dot-phase role: 2 outputs per thread (same row, batches b0 and b0+8)
    const int b_loc = tid >> 5;            // 0..7
    const int r_loc = tid & 31;            // 0..31
    const int gate  = r_loc >> 3;          // 0..3 (i,f,g,o)
    const int uj    = r_loc & 7;
    const int row   = gate * HH + rt * 8 + uj;
    const int b0    = bt * 16 + b_loc;
    const int b1    = b0 + 8;
    const float  wih   = Wih[row];
    const float  biasr = bih[row] + bhh[row];
    const float4* wrow = (const float4*)(Whh + row * HH);  // 128 float4s, L1-hot

    // ---- update-phase role (tid < 128): unit (b2, u_loc)
    const int b2    = tid >> 3;            // 0..15
    const int u_loc = tid & 7;
    const int ug    = rt * 8 + u_loc;      // global unit index
    const float wfc  = Wfc[ug];
    const float bfcv = bfc[0];
    float c = 0.0f;                        // cell state lives in a register

    for (int t = 0; t < TT; ++t) {
        // stage h_prev tile: 16 batches x 512 contiguous floats
        {
            const float4* src = (const float4*)(hbuf + (t & 1) * BB * HH + bt * 16 * HH);
            float4* dst = (float4*)hs;
#pragma unroll
            for (int i = 0; i < 8; ++i) dst[i * 256 + tid] = src[i * 256 + tid];
        }
        __syncthreads();

        // gate preactivation: x-projection + h . W_hh_row
        float acc0 = fmaf(x[b0 * TT + t], wih, biasr);
        float acc1 = fmaf(x[b1 * TT + t], wih, biasr);
        const float4* h0p = (const float4*)(hs + b_loc * HH);
        const float4* h1p = (const float4*)(hs + (b_loc + 8) * HH);
#pragma unroll 4
        for (int k4 = 0; k4 < 128; ++k4) {
            const float4 wv = wrow[k4];
            const float4 ha = h0p[k4];   // broadcast within wave-half (same addr)
            const float4 hb = h1p[k4];
            acc0 = fmaf(wv.x, ha.x, acc0); acc0 = fmaf(wv.y, ha.y, acc0);
            acc0 = fmaf(wv.z, ha.z, acc0); acc0 = fmaf(wv.w, ha.w, acc0);
            acc1 = fmaf(wv.x, hb.x, acc1); acc1 = fmaf(wv.y, hb.y, acc1);
            acc1 = fmaf(wv.z, hb.z, acc1); acc1 = fmaf(wv.w, hb.w, acc1);
        }
        gs[b_loc][r_loc]     = acc0;
        gs[b_loc + 8][r_loc] = acc1;
        __syncthreads();

        if (tid < 128) {
            const float pi = gs[b2][u_loc];
            const float pf = gs[b2][8 + u_loc];
            const float pg = gs[b2][16 + u_loc];
            const float po = gs[b2][24 + u_loc];
            const float ig = 1.0f / (1.0f + __expf(-pi));
            const float fg = 1.0f / (1.0f + __expf(-pf));
            const float gg = 2.0f / (1.0f + __expf(-2.0f * pg)) - 1.0f;  // tanh
            const float og = 1.0f / (1.0f + __expf(-po));
            c = fmaf(fg, c, ig * gg);
            const float tc = 2.0f / (1.0f + __expf(-2.0f * c)) - 1.0f;
            const float h  = og * tc;
            const int   b  = bt * 16 + b2;
            hbuf[((t + 1) & 1) * BB * HH + b * HH + ug] = h;

            // y[b][t] partial: reduce 8 units within the wave, one atomic per (WG,b)
            float yp = h * wfc;
            yp += __shfl_down(yp, 4, 8);
            yp += __shfl_down(yp, 2, 8);
            yp += __shfl_down(yp, 1, 8);
            if (u_loc == 0) {
                if (rt == 0) yp += bfcv;
                atomicAdd(out + Y_OFF + b * TT + t, yp);  // fire-and-forget
            }
            if (t == TT - 1) {
                out[HN_OFF + b * HH + ug] = h;
                out[CN_OFF + b * HH + ug] = c;
            }
        }
        grid_barrier(cnt, t);
    }
}

extern "C" void kernel_launch(void* const* d_in, const int* in_sizes, int n_in,
                              void* d_out, int out_size, void* d_ws, size_t ws_size,
                              hipStream_t stream) {
    const float* x   = (const float*)d_in[0];
    const float* Wih = (const float*)d_in[1];
    const float* Whh = (const float*)d_in[2];
    const float* bih = (const float*)d_in[3];
    const float* bhh = (const float*)d_in[4];
    const float* Wfc = (const float*)d_in[5];
    const float* bfc = (const float*)d_in[6];
    float* out = (float*)d_out;

    // ws layout: [0,4096): barrier counters; [4096, 4096+256KB): hbuf[2][64][512]
    unsigned* cnt  = (unsigned*)d_ws;
    float*    hbuf = (float*)((char*)d_ws + 4096);

    // zero counters + h double-buffer + the y region of out (atomicAdd target)
    hipMemsetAsync(d_ws, 0, 4096 + 2 * BB * HH * sizeof(float), stream);
    hipMemsetAsync(d_out, 0, BB * TT * sizeof(float), stream);

    lstm_persistent<<<dim3(256), dim3(256), 0, stream>>>(
        x, Wih, Whh, bih, bhh, Wfc, bfc, out, hbuf, cnt);
}

// Round 2
// 22013.161 us; speedup vs baseline: 2.7757x; 2.7757x over previous
//
#include <hip/hip_runtime.h>

// SimpleLSTM B=64, T=2048, H=512. Round 2: 4 independent groups of 64 blocks
// (group g = batches g*16..+16; block r = units r*8..+8, all 4 gates = 32 rows).
// Per-group dataflow sync via one monotonic release/acquire counter (64 arrivals,
// no global barrier). Dot = mfma_f32_16x16x32_bf16 with hi/lo split (3-term,
// fp32-grade). W fragments persistent in registers (K split across 4 waves);
// h ring buffer (4 slots) stored as hi/lo bf16 planes, consumed directly as
// A-fragments from global. LDS only for cross-wave partial-C reduction (9 KB).

#define TT 2048
#define BB 64
#define HH 512
#define Y_OFF 0
#define HN_OFF (BB * TT)
#define CN_OFF (BB * TT + BB * HH)
#define DEPTH 4
#define PLANE 8192  // 16*512 bf16 elements per (group,plane,slot) tile

typedef short short8 __attribute__((ext_vector_type(8)));
typedef float f32x4  __attribute__((ext_vector_type(4)));

__device__ __forceinline__ unsigned short f2bf(float f) {  // RNE fp32->bf16 bits
    unsigned u = __float_as_uint(f);
    return (unsigned short)((u + 0x7fffu + ((u >> 16) & 1u)) >> 16);
}
__device__ __forceinline__ float bf2f(unsigned short h) {
    return __uint_as_float(((unsigned)h) << 16);
}

__device__ __forceinline__ void wait_ge(unsigned* c, unsigned tgt) {
    while (__hip_atomic_load(c, __ATOMIC_ACQUIRE, __HIP_MEMORY_SCOPE_AGENT) < tgt)
        __builtin_amdgcn_s_sleep(1);
}

__global__ __launch_bounds__(256, 1)
void lstm_mfma(const float* __restrict__ x,     // [B][T]
               const float* __restrict__ Wih,   // [4H]
               const float* __restrict__ Whh,   // [4H][H]
               const float* __restrict__ bih,   // [4H]
               const float* __restrict__ bhh,   // [4H]
               const float* __restrict__ Wfc,   // [H]
               const float* __restrict__ bfc,   // [1]
               float* __restrict__ out,         // y | h_n | c_n
               unsigned short* __restrict__ hb, // h ring: [g][plane][slot][16][512] bf16
               unsigned* __restrict__ cnt)      // done counters, 128B apart per group
{
    const int g    = blockIdx.x & 3;
    const int rt   = blockIdx.x >> 2;   // 0..63: unit tile
    const int tid  = threadIdx.x;
    const int wid  = tid >> 6;          // wave 0..3 -> K-slice wid*128..+128
    const int lane = tid & 63;
    const int quad = lane >> 4;
    const int l16  = lane & 15;

    __shared__ float gsp[4][16][36];    // per-wave partial C tiles, padded

    // ---- persistent W fragments (hi/lo split) for this wave's K-slice ----
    // tile tl covers local rows tl*16..+16; local row rl = gate*8 + uj
    short8 whi[2][4], wlo[2][4];
#pragma unroll
    for (int tl = 0; tl < 2; ++tl) {
        const int rl   = tl * 16 + l16;
        const int grow = (rl >> 3) * HH + rt * 8 + (rl & 7);
#pragma unroll
        for (int ki = 0; ki < 4; ++ki) {
            const int k = wid * 128 + ki * 32 + quad * 8;
            const float* wp = Whh + grow * HH + k;
            short8 h8, l8;
#pragma unroll
            for (int j = 0; j < 8; ++j) {
                const float f = wp[j];
                const unsigned short hi = f2bf(f);
                h8[j] = (short)hi;
                l8[j] = (short)f2bf(f - bf2f(hi));
            }
            whi[tl][ki] = h8;
            wlo[tl][ki] = l8;
        }
    }

    // ---- epilogue role (tid < 128): unit (b2, u) ----
    const int b2    = tid >> 3;         // 0..15
    const int u     = tid & 7;
    const int bglob = g * 16 + b2;
    const int ug    = rt * 8 + u;
    float wih4[4], bia4[4];
#pragma unroll
    for (int gi = 0; gi < 4; ++gi) {
        const int grow = gi * HH + ug;
        wih4[gi] = Wih[grow];
        bia4[gi] = bih[grow] + bhh[grow];
    }
    const float wfc  = Wfc[ug];
    const float bfcv = bfc[0];
    float c = 0.0f;

    unsigned* dcnt = cnt + g * 32;
    const unsigned base_hi = (unsigned)((g * 2 + 0) * DEPTH);
    const unsigned base_lo = (unsigned)((g * 2 + 1) * DEPTH);

    for (int t = 0; t < TT; ++t) {
        // ---- wait for state t (all 64 group members finished step t-1) ----
        if (tid == 0) wait_ge(dcnt, (unsigned)t * 64u);
        __syncthreads();  // B1: acquire + broadcast

        // ---- dot: A = H[16 x 512] from ring slot t&3, this wave's K-slice ----
        const unsigned short* Ah = hb + (base_hi + (t & 3)) * PLANE + l16 * HH;
        const unsigned short* Al = hb + (base_lo + (t & 3)) * PLANE + l16 * HH;
        f32x4 a0 = {0.f, 0.f, 0.f, 0.f};
        f32x4 a1 = {0.f, 0.f, 0.f, 0.f};
#pragma unroll
        for (int ki = 0; ki < 4; ++ki) {
            const int k = wid * 128 + ki * 32 + quad * 8;
            const short8 ah = *(const short8*)(Ah + k);
            const short8 al = *(const short8*)(Al + k);
            a0 = __builtin_amdgcn_mfma_f32_16x16x32_bf16(ah, whi[0][ki], a0, 0, 0, 0);
            a1 = __builtin_amdgcn_mfma_f32_16x16x32_bf16(ah, whi[1][ki], a1, 0, 0, 0);
            a0 = __builtin_amdgcn_mfma_f32_16x16x32_bf16(al, whi[0][ki], a0, 0, 0, 0);
            a1 = __builtin_amdgcn_mfma_f32_16x16x32_bf16(al, whi[1][ki], a1, 0, 0, 0);
            a0 = __builtin_amdgcn_mfma_f32_16x16x32_bf16(ah, wlo[0][ki], a0, 0, 0, 0);
            a1 = __builtin_amdgcn_mfma_f32_16x16x32_bf16(ah, wlo[1][ki], a1, 0, 0, 0);
        }
        // D layout: col = lane&15 (= local row), row = quad*4+reg (= batch)
#pragma unroll
        for (int r = 0; r < 4; ++r) {
            gsp[wid][quad * 4 + r][l16]      = a0[r];
            gsp[wid][quad * 4 + r][16 + l16] = a1[r];
        }
        __syncthreads();  // B2

        if (tid < 128) {
            float pre[4];
#pragma unroll
            for (int gi = 0; gi < 4; ++gi) {
                float s = 0.f;
#pragma unroll
                for (int w = 0; w < 4; ++w) s += gsp[w][b2][gi * 8 + u];
                pre[gi] = fmaf(x[bglob * TT + t], wih4[gi], bia4[gi]) + s;
            }
            const float ig = 1.f / (1.f + __expf(-pre[0]));
            const float fg = 1.f / (1.f + __expf(-pre[1]));
            const float gg = 2.f / (1.f + __expf(-2.f * pre[2])) - 1.f;
            const float og = 1.f / (1.f + __expf(-pre[3]));
            c = fmaf(fg, c, ig * gg);
            const float tc = 2.f / (1.f + __expf(-2.f * c)) - 1.f;
            const float h  = og * tc;

            // store h as hi/lo bf16 planes into ring slot (t+1)&3
            const int slot = (t + 1) & 3;
            const unsigned short hh = f2bf(h);
            const unsigned short hl = f2bf(h - bf2f(hh));
            hb[(base_hi + slot) * PLANE + b2 * HH + ug] = hh;
            hb[(base_lo + slot) * PLANE + b2 * HH + ug] = hl;

            // y[b][t]: reduce 8 units, one atomic per (block, b)
            float yp = h * wfc;
            yp += __shfl_down(yp, 4, 8);
            yp += __shfl_down(yp, 2, 8);
            yp += __shfl_down(yp, 1, 8);
            if (u == 0) {
                if (rt == 0) yp += bfcv;
                atomicAdd(out + Y_OFF + bglob * TT + t, yp);
            }
            if (t == TT - 1) {
                out[HN_OFF + bglob * HH + ug] = h;
                out[CN_OFF + bglob * HH + ug] = c;
            }
        }
        __syncthreads();  // B3: drain h stores
        if (tid == 0)
            __hip_atomic_fetch_add(dcnt, 1u, __ATOMIC_RELEASE, __HIP_MEMORY_SCOPE_AGENT);
    }
}

extern "C" void kernel_launch(void* const* d_in, const int* in_sizes, int n_in,
                              void* d_out, int out_size, void* d_ws, size_t ws_size,
                              hipStream_t stream) {
    const float* x   = (const float*)d_in[0];
    const float* Wih = (const float*)d_in[1];
    const float* Whh = (const float*)d_in[2];
    const float* bih = (const float*)d_in[3];
    const float* bhh = (const float*)d_in[4];
    const float* Wfc = (const float*)d_in[5];
    const float* bfc = (const float*)d_in[6];
    float* out = (float*)d_out;

    // ws: [0,4096) counters; [4096, 4096+512KB) h ring (4 groups x 2 planes x
    // 4 slots x 16 x 512 bf16)
    unsigned*       cnt = (unsigned*)d_ws;
    unsigned short* hb  = (unsigned short*)((char*)d_ws + 4096);

    hipMemsetAsync(d_ws, 0, 4096 + 4 * 2 * DEPTH * PLANE * sizeof(unsigned short), stream);
    hipMemsetAsync(d_out, 0, BB * TT * sizeof(float), stream);  // atomicAdd target

    lstm_mfma<<<dim3(256), dim3(256), 0, stream>>>(
        x, Wih, Whh, bih, bhh, Wfc, bfc, out, hb, cnt);
}

// Round 3
// 7829.759 us; speedup vs baseline: 7.8039x; 2.8115x over previous
//
#include <hip/hip_runtime.h>

// SimpleLSTM B=64, T=2048, H=512. Round 3: same dataflow as Round 2
// (4 independent groups of 64 blocks; MFMA hi/lo bf16 3-term dot; W persistent
// in registers) but ALL cross-block communication via relaxed agent-scope
// atomics (= sc1 cache-BYPASS ops at the MALL). No acquire/release anywhere in
// the hot loop -> no buffer_inv / buffer_wbl2 L2 flushes (the Round-2 killer:
// 300MB FETCH / 800MB WRITE of pure cache-flush refetch).
// Ordering: producer h-stores (sc1) are vmcnt-drained by __syncthreads before
// the relaxed counter bump; consumer bypass loads read the MALL directly.

#define TT 2048
#define BB 64
#define HH 512
#define Y_OFF 0
#define HN_OFF (BB * TT)
#define CN_OFF (BB * TT + BB * HH)
#define DEPTH 4
#define PLANE 8192  // 16*512 bf16 elements per (group,plane,slot) tile

typedef short short8 __attribute__((ext_vector_type(8)));
typedef float f32x4  __attribute__((ext_vector_type(4)));

__device__ __forceinline__ unsigned f2bf(float f) {  // RNE fp32->bf16 bits
    unsigned u = __float_as_uint(f);
    return (u + 0x7fffu + ((u >> 16) & 1u)) >> 16;
}
__device__ __forceinline__ float bf2f(unsigned h) {
    return __uint_as_float(h << 16);
}

// 16B A-fragment from the MALL (two relaxed agent b64 loads = sc1 bypass)
__device__ __forceinline__ short8 ld_bypass16(const unsigned short* p) {
    unsigned long long q0 = __hip_atomic_load((const unsigned long long*)p,
                                              __ATOMIC_RELAXED, __HIP_MEMORY_SCOPE_AGENT);
    unsigned long long q1 = __hip_atomic_load((const unsigned long long*)(p + 4),
                                              __ATOMIC_RELAXED, __HIP_MEMORY_SCOPE_AGENT);
    union { unsigned long long q[2]; short8 s; } u;
    u.q[0] = q0; u.q[1] = q1;
    return u.s;
}

__global__ __launch_bounds__(256, 1)
void lstm_mfma(const float* __restrict__ x,     // [B][T]
               const float* __restrict__ Wih,   // [4H]
               const float* __restrict__ Whh,   // [4H][H]
               const float* __restrict__ bih,   // [4H]
               const float* __restrict__ bhh,   // [4H]
               const float* __restrict__ Wfc,   // [H]
               const float* __restrict__ bfc,   // [1]
               float* __restrict__ out,         // y | h_n | c_n
               unsigned short* __restrict__ hb, // h ring: [g][plane][slot][16][512] bf16
               unsigned* __restrict__ cnt)      // done counters, 128B apart per group
{
    const int g    = blockIdx.x & 3;
    const int rt   = blockIdx.x >> 2;   // 0..63: unit tile
    const int tid  = threadIdx.x;
    const int wid  = tid >> 6;          // wave 0..3 -> K-slice wid*128..+128
    const int lane = tid & 63;
    const int quad = lane >> 4;
    const int l16  = lane & 15;

    __shared__ float gsp[4][16][36];    // per-wave partial C tiles, padded

    // ---- persistent W fragments (hi/lo split) for this wave's K-slice ----
    short8 whi[2][4], wlo[2][4];
#pragma unroll
    for (int tl = 0; tl < 2; ++tl) {
        const int rl   = tl * 16 + l16;
        const int grow = (rl >> 3) * HH + rt * 8 + (rl & 7);
#pragma unroll
        for (int ki = 0; ki < 4; ++ki) {
            const int k = wid * 128 + ki * 32 + quad * 8;
            const float* wp = Whh + grow * HH + k;
            short8 h8, l8;
#pragma unroll
            for (int j = 0; j < 8; ++j) {
                const float f = wp[j];
                const unsigned hi = f2bf(f);
                h8[j] = (short)hi;
                l8[j] = (short)f2bf(f - bf2f(hi));
            }
            whi[tl][ki] = h8;
            wlo[tl][ki] = l8;
        }
    }

    // ---- epilogue role (tid < 128): unit (b2, u) ----
    const int b2    = tid >> 3;         // 0..15
    const int u     = tid & 7;
    const int bglob = g * 16 + b2;
    const int ug    = rt * 8 + u;
    float wih4[4], bia4[4];
#pragma unroll
    for (int gi = 0; gi < 4; ++gi) {
        const int grow = gi * HH + ug;
        wih4[gi] = Wih[grow];
        bia4[gi] = bih[grow] + bhh[grow];
    }
    const float wfc  = Wfc[ug];
    const float bfcv = bfc[0];
    float c = 0.0f;

    unsigned* dcnt = cnt + g * 32;
    const unsigned base_hi = (unsigned)((g * 2 + 0) * DEPTH);
    const unsigned base_lo = (unsigned)((g * 2 + 1) * DEPTH);
    unsigned* hb32 = (unsigned*)hb;

    for (int t = 0; t < TT; ++t) {
        // ---- wait for state t: relaxed poll (NO acquire -> no buffer_inv) ----
        if (tid == 0) {
            const unsigned tgt = (unsigned)t * 64u;
            while (__hip_atomic_load(dcnt, __ATOMIC_RELAXED, __HIP_MEMORY_SCOPE_AGENT) < tgt)
                __builtin_amdgcn_s_sleep(1);
        }
        __syncthreads();  // B1

        // ---- dot: A = H[16 x 512] from ring slot t&3 via MALL-bypass loads ----
        const unsigned short* Ah = hb + (base_hi + (t & 3)) * PLANE + l16 * HH;
        const unsigned short* Al = hb + (base_lo + (t & 3)) * PLANE + l16 * HH;
        f32x4 a0 = {0.f, 0.f, 0.f, 0.f};
        f32x4 a1 = {0.f, 0.f, 0.f, 0.f};
#pragma unroll
        for (int ki = 0; ki < 4; ++ki) {
            const int k = wid * 128 + ki * 32 + quad * 8;
            const short8 ah = ld_bypass16(Ah + k);
            const short8 al = ld_bypass16(Al + k);
            a0 = __builtin_amdgcn_mfma_f32_16x16x32_bf16(ah, whi[0][ki], a0, 0, 0, 0);
            a1 = __builtin_amdgcn_mfma_f32_16x16x32_bf16(ah, whi[1][ki], a1, 0, 0, 0);
            a0 = __builtin_amdgcn_mfma_f32_16x16x32_bf16(al, whi[0][ki], a0, 0, 0, 0);
            a1 = __builtin_amdgcn_mfma_f32_16x16x32_bf16(al, whi[1][ki], a1, 0, 0, 0);
            a0 = __builtin_amdgcn_mfma_f32_16x16x32_bf16(ah, wlo[0][ki], a0, 0, 0, 0);
            a1 = __builtin_amdgcn_mfma_f32_16x16x32_bf16(ah, wlo[1][ki], a1, 0, 0, 0);
        }
        // D layout: col = lane&15 (= local row), row = quad*4+reg (= batch)
#pragma unroll
        for (int r = 0; r < 4; ++r) {
            gsp[wid][quad * 4 + r][l16]      = a0[r];
            gsp[wid][quad * 4 + r][16 + l16] = a1[r];
        }
        __syncthreads();  // B2

        if (tid < 128) {
            float pre[4];
#pragma unroll
            for (int gi = 0; gi < 4; ++gi) {
                float s = 0.f;
#pragma unroll
                for (int w = 0; w < 4; ++w) s += gsp[w][b2][gi * 8 + u];
                pre[gi] = fmaf(x[bglob * TT + t], wih4[gi], bia4[gi]) + s;
            }
            const float ig = 1.f / (1.f + __expf(-pre[0]));
            const float fg = 1.f / (1.f + __expf(-pre[1]));
            const float gg = 2.f / (1.f + __expf(-2.f * pre[2])) - 1.f;
            const float og = 1.f / (1.f + __expf(-pre[3]));
            c = fmaf(fg, c, ig * gg);
            const float tc = 2.f / (1.f + __expf(-2.f * c)) - 1.f;
            const float h  = og * tc;

            // ---- h -> ring slot (t+1)&3 as hi/lo bf16 planes, sc1 stores ----
            // pack self (hh | hl<<16), pair with u^1 lane, even-u lane stores
            // one dword per plane: memory order [ug, ug+1].
            const unsigned hh = f2bf(h);
            const unsigned hl = f2bf(h - bf2f(hh));
            const unsigned packed = hh | (hl << 16);
            const unsigned part = (unsigned)__shfl_xor((int)packed, 1, 64);
            if ((u & 1) == 0) {
                const unsigned sH = __builtin_amdgcn_perm(part, packed, 0x05040100u);
                const unsigned sL = __builtin_amdgcn_perm(part, packed, 0x07060302u);
                const int slot    = (t + 1) & 3;
                const int pairidx = (b2 * HH + ug) >> 1;
                __hip_atomic_store(hb32 + (base_hi + slot) * (PLANE / 2) + pairidx, sH,
                                   __ATOMIC_RELAXED, __HIP_MEMORY_SCOPE_AGENT);
                __hip_atomic_store(hb32 + (base_lo + slot) * (PLANE / 2) + pairidx, sL,
                                   __ATOMIC_RELAXED, __HIP_MEMORY_SCOPE_AGENT);
            }

            // y[b][t]: reduce 8 units, one atomic per (block, b)
            float yp = h * wfc;
            yp += __shfl_down(yp, 4, 8);
            yp += __shfl_down(yp, 2, 8);
            yp += __shfl_down(yp, 1, 8);
            if (u == 0) {
                if (rt == 0) yp += bfcv;
                atomicAdd(out + Y_OFF + bglob * TT + t, yp);
            }
            if (t == TT - 1) {
                out[HN_OFF + bglob * HH + ug] = h;
                out[CN_OFF + bglob * HH + ug] = c;
            }
        }
        // B3: each wave drains its own sc1 stores (vmcnt(0)) before the barrier,
        // so the relaxed bump below is release-ordered at the MALL w/o wbl2.
        __syncthreads();
        if (tid == 0)
            __hip_atomic_fetch_add(dcnt, 1u, __ATOMIC_RELAXED, __HIP_MEMORY_SCOPE_AGENT);
    }
}

extern "C" void kernel_launch(void* const* d_in, const int* in_sizes, int n_in,
                              void* d_out, int out_size, void* d_ws, size_t ws_size,
                              hipStream_t stream) {
    const float* x   = (const float*)d_in[0];
    const float* Wih = (const float*)d_in[1];
    const float* Whh = (const float*)d_in[2];
    const float* bih = (const float*)d_in[3];
    const float* bhh = (const float*)d_in[4];
    const float* Wfc = (const float*)d_in[5];
    const float* bfc = (const float*)d_in[6];
    float* out = (float*)d_out;

    // ws: [0,4096) counters; [4096, 4096+512KB) h ring
    unsigned*       cnt = (unsigned*)d_ws;
    unsigned short* hb  = (unsigned short*)((char*)d_ws + 4096);

    hipMemsetAsync(d_ws, 0, 4096 + 4 * 2 * DEPTH * PLANE * sizeof(unsigned short), stream);
    hipMemsetAsync(d_out, 0, BB * TT * sizeof(float), stream);  // atomicAdd target

    lstm_mfma<<<dim3(256), dim3(256), 0, stream>>>(
        x, Wih, Whh, bih, bhh, Wfc, bfc, out, hb, cnt);
}

// Round 6
// 5914.011 us; speedup vs baseline: 10.3319x; 1.3239x over previous
//
#include <hip/hip_runtime.h>

// SimpleLSTM B=64, T=2048, H=512. Round 6: XCD-local recurrence, hang-proofed.
// 8 groups x 8 batches x 32 blocks, 64 rows/block, W hi/lo bf16 frags in VGPRs.
// Counters/sync ALWAYS via relaxed agent (sc1/MALL) ops (R3-proven). Bulk data
// (h ring, y adds) XCD-local in FAST mode: plain write-through stores + sc0
// loads — enabled per-group only after a runtime coherence PROBE of exactly
// that mechanism passes. Probe + init use only unconditionally-terminating
// agent-scope waits. Fallback: R3-proven sc1 everywhere.

#define TT 2048
#define BB 64
#define HH 512
#define GB 8            // batches per group
#define NBLK 32         // blocks per group
#define DEPTH 4
#define PLANE (GB * HH) // 4096 bf16 per plane-slot (8 KB)
#define Y_OFF 0
#define HN_OFF (BB * TT)
#define CN_OFF (BB * TT + BB * HH)

typedef short short8 __attribute__((ext_vector_type(8)));
typedef float f32x4  __attribute__((ext_vector_type(4)));

__device__ __forceinline__ unsigned f2bf(float f) {  // RNE fp32->bf16 bits
    unsigned u = __float_as_uint(f);
    return (u + 0x7fffu + ((u >> 16) & 1u)) >> 16;
}
__device__ __forceinline__ float bf2f(unsigned h) { return __uint_as_float(h << 16); }

// ---- relaxed agent-scope (sc1/MALL) primitives — R3-proven ----------------
__device__ __forceinline__ unsigned ld_agent(const unsigned* p) {
    return __hip_atomic_load(p, __ATOMIC_RELAXED, __HIP_MEMORY_SCOPE_AGENT);
}
__device__ __forceinline__ void st_agent(unsigned* p, unsigned v) {
    __hip_atomic_store(p, v, __ATOMIC_RELAXED, __HIP_MEMORY_SCOPE_AGENT);
}
__device__ __forceinline__ unsigned add_agent(unsigned* p, unsigned v) {
    return __hip_atomic_fetch_add(p, v, __ATOMIC_RELAXED, __HIP_MEMORY_SCOPE_AGENT);
}
__device__ __forceinline__ short8 ld_sc1_b128(const unsigned short* p) {
    unsigned long long q0 = __hip_atomic_load((const unsigned long long*)p,
                                              __ATOMIC_RELAXED, __HIP_MEMORY_SCOPE_AGENT);
    unsigned long long q1 = __hip_atomic_load((const unsigned long long*)(p + 4),
                                              __ATOMIC_RELAXED, __HIP_MEMORY_SCOPE_AGENT);
    union { unsigned long long q[2]; short8 s; } u;
    u.q[0] = q0; u.q[1] = q1;
    return u.s;
}

// ---- sc0 (L1-bypass, XCD-L2) data loads: FAST path only, probe-gated ------
__device__ __forceinline__ void ld_sc0_8x128(const void* pa, const void* pb,
                                             short8* A, short8* B) {
    asm volatile(
        "global_load_dwordx4 %0, %[pa], off sc0\n\t"
        "global_load_dwordx4 %1, %[pa], off offset:64 sc0\n\t"
        "global_load_dwordx4 %2, %[pa], off offset:128 sc0\n\t"
        "global_load_dwordx4 %3, %[pa], off offset:192 sc0\n\t"
        "global_load_dwordx4 %4, %[pb], off sc0\n\t"
        "global_load_dwordx4 %5, %[pb], off offset:64 sc0\n\t"
        "global_load_dwordx4 %6, %[pb], off offset:128 sc0\n\t"
        "global_load_dwordx4 %7, %[pb], off offset:192 sc0\n\t"
        "s_waitcnt vmcnt(0)"
        : "=&v"(A[0]), "=&v"(A[1]), "=&v"(A[2]), "=&v"(A[3]),
          "=&v"(B[0]), "=&v"(B[1]), "=&v"(B[2]), "=&v"(B[3])
        : [pa] "v"(pa), [pb] "v"(pb)
        : "memory");
}
__device__ __forceinline__ uint4 ld_sc0_probe(const void* p) {
    uint4 d;
    asm volatile("global_load_dwordx4 %0, %1, off sc0\n\ts_waitcnt vmcnt(0)"
                 : "=&v"(d) : "v"(p) : "memory");
    return d;
}

#define GSP(w, tl, r, c) gsp[((((w) * 4 + (tl)) * 16 + (r)) * 20) + (c)]

template <bool FAST>
__device__ __noinline__ void run_loop(
    const float* __restrict__ x, const float* __restrict__ Whh,
    const float* __restrict__ Wih, const float* __restrict__ bih,
    const float* __restrict__ bhh, const float* __restrict__ Wfc,
    const float* __restrict__ bfc, float* __restrict__ out,
    unsigned short* __restrict__ hb, unsigned* __restrict__ stepc,
    const int grp, const int ut, float* gsp)
{
    const int tid  = threadIdx.x;
    const int wid  = tid >> 6;          // wave 0..3 -> K-slice wid*128..+128
    const int lane = tid & 63;
    const int quad = lane >> 4;
    const int l16  = lane & 15;

    // ---- persistent W fragments (hi/lo split); tile tl = gate, 16 units ----
    short8 whi[4][4], wlo[4][4];
#pragma unroll
    for (int tl = 0; tl < 4; ++tl) {
        const int grow  = tl * HH + ut * 16 + l16;   // row = gate*512 + unit
        const float* wr = Whh + grow * HH + wid * 128 + quad * 8;
#pragma unroll
        for (int ki = 0; ki < 4; ++ki) {
            const float* wp = wr + ki * 32;
            short8 h8, l8;
#pragma unroll
            for (int j = 0; j < 8; ++j) {
                const float f = wp[j];
                const unsigned hi = f2bf(f);
                h8[j] = (short)hi;
                l8[j] = (short)f2bf(f - bf2f(hi));
            }
            whi[tl][ki] = h8;
            wlo[tl][ki] = l8;
        }
    }

    // ---- epilogue role (tid < 128): batch b2, unit u ----
    const int b2    = (tid >> 4) & 7;
    const int u     = tid & 15;
    const int bglob = grp * GB + b2;
    const int ug    = ut * 16 + u;
    float wih4[4], bia4[4];
#pragma unroll
    for (int gi = 0; gi < 4; ++gi) {
        const int grow = gi * HH + ug;
        wih4[gi] = Wih[grow];
        bia4[gi] = bih[grow] + bhh[grow];
    }
    const float wfc  = Wfc[ug];
    const float bfcv = bfc[0];
    float c = 0.0f;

    const int base_hi = grp * 2 * DEPTH;
    const int base_lo = base_hi + DEPTH;
    unsigned* hb32 = (unsigned*)hb;
    const unsigned* pollp = stepc + (tid & 31);

    for (int t = 0; t < TT; ++t) {
        // ---- B1: min-barrier over the group's 32 per-block step counters ----
        if (tid < 64) {
            const unsigned tgt = (unsigned)t;
            for (;;) {
                const unsigned v = ld_agent(pollp);   // sc1: always coherent
                if (__all((int)(v >= tgt))) break;
            }
        }
        __syncthreads();

        const float xv = x[bglob * TT + t];

        // ---- A = H[8(dup16) x 512] from ring slot t&3, this wave's K-slice ----
        const unsigned short* Ah =
            hb + (base_hi + (t & 3)) * PLANE + (l16 & 7) * HH + wid * 128 + quad * 8;
        const unsigned short* Al =
            hb + (base_lo + (t & 3)) * PLANE + (l16 & 7) * HH + wid * 128 + quad * 8;
        short8 ah[4], al[4];
        if constexpr (FAST) {
            ld_sc0_8x128(Ah, Al, ah, al);   // XCD-L2 local, L1-bypassed
        } else {
#pragma unroll
            for (int ki = 0; ki < 4; ++ki) {
                ah[ki] = ld_sc1_b128(Ah + ki * 32);
                al[ki] = ld_sc1_b128(Al + ki * 32);
            }
        }

        f32x4 acc[4] = {{0.f,0.f,0.f,0.f},{0.f,0.f,0.f,0.f},
                        {0.f,0.f,0.f,0.f},{0.f,0.f,0.f,0.f}};
#pragma unroll
        for (int ki = 0; ki < 4; ++ki) {
#pragma unroll
            for (int tl = 0; tl < 4; ++tl)
                acc[tl] = __builtin_amdgcn_mfma_f32_16x16x32_bf16(ah[ki], whi[tl][ki], acc[tl], 0, 0, 0);
#pragma unroll
            for (int tl = 0; tl < 4; ++tl)
                acc[tl] = __builtin_amdgcn_mfma_f32_16x16x32_bf16(al[ki], whi[tl][ki], acc[tl], 0, 0, 0);
#pragma unroll
            for (int tl = 0; tl < 4; ++tl)
                acc[tl] = __builtin_amdgcn_mfma_f32_16x16x32_bf16(ah[ki], wlo[tl][ki], acc[tl], 0, 0, 0);
        }
        // D: col=lane&15 (unit), row=quad*4+reg (batch; rows 8..15 are dups)
#pragma unroll
        for (int tl = 0; tl < 4; ++tl)
#pragma unroll
            for (int r = 0; r < 4; ++r)
                GSP(wid, tl, quad * 4 + r, l16) = acc[tl][r];
        __syncthreads();  // B2

        if (tid < 128) {
            float pre[4];
#pragma unroll
            for (int gi = 0; gi < 4; ++gi) {
                float s = 0.f;
#pragma unroll
                for (int w = 0; w < 4; ++w) s += GSP(w, gi, b2, u);
                pre[gi] = fmaf(xv, wih4[gi], bia4[gi]) + s;
            }
            const float ig = 1.f / (1.f + __expf(-pre[0]));
            const float fg = 1.f / (1.f + __expf(-pre[1]));
            const float gg = 2.f / (1.f + __expf(-2.f * pre[2])) - 1.f;
            const float og = 1.f / (1.f + __expf(-pre[3]));
            c = fmaf(fg, c, ig * gg);
            const float tc = 2.f / (1.f + __expf(-2.f * c)) - 1.f;
            const float h  = og * tc;

            // ---- h -> ring slot (t+1)&3, hi/lo planes, paired dword stores ----
            const unsigned hh = f2bf(h);
            const unsigned hl = f2bf(h - bf2f(hh));
            const unsigned packed = hh | (hl << 16);
            const unsigned part = (unsigned)__shfl_xor((int)packed, 1, 64);
            if ((u & 1) == 0) {
                const unsigned sH = __builtin_amdgcn_perm(part, packed, 0x05040100u);
                const unsigned sL = __builtin_amdgcn_perm(part, packed, 0x07060302u);
                const int slot    = (t + 1) & 3;
                const int pairidx = (b2 * HH + ug) >> 1;
                if constexpr (FAST) {  // plain write-through -> XCD L2 (probed)
                    __hip_atomic_store(hb32 + (base_hi + slot) * (PLANE / 2) + pairidx, sH,
                                       __ATOMIC_RELAXED, __HIP_MEMORY_SCOPE_WORKGROUP);
                    __hip_atomic_store(hb32 + (base_lo + slot) * (PLANE / 2) + pairidx, sL,
                                       __ATOMIC_RELAXED, __HIP_MEMORY_SCOPE_WORKGROUP);
                } else {
                    __hip_atomic_store(hb32 + (base_hi + slot) * (PLANE / 2) + pairidx, sH,
                                       __ATOMIC_RELAXED, __HIP_MEMORY_SCOPE_AGENT);
                    __hip_atomic_store(hb32 + (base_lo + slot) * (PLANE / 2) + pairidx, sL,
                                       __ATOMIC_RELAXED, __HIP_MEMORY_SCOPE_AGENT);
                }
            }

            // y[b][t]: reduce 16 units, one atomic per (block, batch)
            float yp = h * wfc;
            yp += __shfl_down(yp, 8, 16);
            yp += __shfl_down(yp, 4, 16);
            yp += __shfl_down(yp, 2, 16);
            yp += __shfl_down(yp, 1, 16);
            if (u == 0) {
                if (ut == 0) yp += bfcv;
                if constexpr (FAST)  // L2-local add; line is group-exclusive
                    __hip_atomic_fetch_add(out + Y_OFF + bglob * TT + t, yp,
                                           __ATOMIC_RELAXED, __HIP_MEMORY_SCOPE_WORKGROUP);
                else
                    atomicAdd(out + Y_OFF + bglob * TT + t, yp);
            }
            if (t == TT - 1) {
                out[HN_OFF + bglob * HH + ug] = h;
                out[CN_OFF + bglob * HH + ug] = c;
            }
        }
        // B3: compiler emits s_waitcnt vmcnt(0) before s_barrier -> all h
        // stores are in L2 (FAST) / MALL (SLOW) before the counter bump.
        __syncthreads();
        if (tid == 0) st_agent(stepc + ut, (unsigned)(t + 1));  // sc1 always
    }
}

__global__ __launch_bounds__(256, 1)
void lstm_xcd(const float* __restrict__ x, const float* __restrict__ Wih,
              const float* __restrict__ Whh, const float* __restrict__ bih,
              const float* __restrict__ bhh, const float* __restrict__ Wfc,
              const float* __restrict__ bfc, float* __restrict__ out,
              unsigned short* __restrict__ hb, unsigned* __restrict__ cnt)
{
    __shared__ int s_grp, s_ut, s_fast;
    __shared__ float gsp[4 * 4 * 16 * 20];  // 20 KB cross-wave partial-C

    const int tid = threadIdx.x;
    // cnt layout (uints, 16 KB): [0,256) stepc (grp*32+ut); [512,520) claim;
    // [544] bar1; probe data 1024+g*32 (uint4); pflag 1280+g*32;
    // votes_ok 1536+g*32; votes_total 1792+g*32
    unsigned* claim = cnt + 512;
    unsigned* bar1  = cnt + 544;

    if (tid == 0) {
        unsigned xcc;
        asm volatile("s_getreg_b32 %0, hwreg(HW_REG_XCC_ID)" : "=s"(xcc));
        xcc &= 7u;
        const unsigned slot = add_agent(claim + xcc, 1u);
        asm volatile("s_waitcnt vmcnt(0)" ::: "memory");
        add_agent(bar1, 1u);
        while (ld_agent(bar1) < 256u) __builtin_amdgcn_s_sleep(1);
        bool pure = true;
        for (int g2 = 0; g2 < 8; ++g2) pure &= (ld_agent(claim + g2) == (unsigned)NBLK);

        int fast = 0, grp, ut;
        if (pure) {
            grp = (int)xcc; ut = (int)slot;
            // ---- coherence probe of the FAST mechanism (all waits terminate:
            // pflag set unconditionally by ut0; votes reach 32 unconditionally)
            unsigned* probe = cnt + 1024 + grp * 32;
            unsigned* pflag = cnt + 1280 + grp * 32;
            unsigned* v_ok  = cnt + 1536 + grp * 32;
            unsigned* v_tot = cnt + 1792 + grp * 32;
            if (ut == 0) {
                uint4 m = make_uint4(0xC0FFEE42u, 0x5EED5EEDu, 0xA110C8EDu, 0xB16B00B5u);
                *(uint4*)probe = m;                      // plain write-through store
                asm volatile("s_waitcnt vmcnt(0)" ::: "memory");
                st_agent(pflag, 1u);
            }
            while (ld_agent(pflag) == 0u) __builtin_amdgcn_s_sleep(1);
            const uint4 d = ld_sc0_probe(probe);         // the FAST load path
            const unsigned ok = (d.x == 0xC0FFEE42u && d.y == 0x5EED5EEDu &&
                                 d.z == 0xA110C8EDu && d.w == 0xB16B00B5u) ? 1u : 0u;
            add_agent(v_ok, ok);
            asm volatile("s_waitcnt vmcnt(0)" ::: "memory");  // ok before total
            add_agent(v_tot, 1u);
            while (ld_agent(v_tot) < (unsigned)NBLK) __builtin_amdgcn_s_sleep(1);
            fast = (ld_agent(v_ok) == (unsigned)NBLK) ? 1 : 0;
        } else {
            grp = (int)(blockIdx.x >> 5); ut = (int)(blockIdx.x & 31);
        }
        s_grp = grp; s_ut = ut; s_fast = fast;
    }
    __syncthreads();
    const int grp = s_grp, ut = s_ut;
    unsigned* stepc = cnt + grp * 32;

    if (s_fast) run_loop<true >(x, Whh, Wih, bih, bhh, Wfc, bfc, out, hb, stepc, grp, ut, gsp);
    else        run_loop<false>(x, Whh, Wih, bih, bhh, Wfc, bfc, out, hb, stepc, grp, ut, gsp);
}

extern "C" void kernel_launch(void* const* d_in, const int* in_sizes, int n_in,
                              void* d_out, int out_size, void* d_ws, size_t ws_size,
                              hipStream_t stream) {
    const float* x   = (const float*)d_in[0];
    const float* Wih = (const float*)d_in[1];
    const float* Whh = (const float*)d_in[2];
    const float* bih = (const float*)d_in[3];
    const float* bhh = (const float*)d_in[4];
    const float* Wfc = (const float*)d_in[5];
    const float* bfc = (const float*)d_in[6];
    float* out = (float*)d_out;

    // ws: [0,16K) counters/claims/probe; [16K, 16K+512K) h ring
    unsigned*       cnt = (unsigned*)d_ws;
    unsigned short* hb  = (unsigned short*)((char*)d_ws + 16384);

    hipMemsetAsync(d_ws, 0, 16384 + 8 * 2 * DEPTH * PLANE * sizeof(unsigned short), stream);
    hipMemsetAsync(d_out, 0, BB * TT * sizeof(float), stream);  // atomic target

    lstm_xcd<<<dim3(256), dim3(256), 0, stream>>>(
        x, Wih, Whh, bih, bhh, Wfc, bfc, out, hb, cnt);
}